// Round 1
// baseline (924.256 us; speedup 1.0000x reference)
//
#include <hip/hip_runtime.h>

#define N 32768
#define F 768
#define C 64
#define P 8192

// ---------------- workspace layout (float offsets) ----------------
#define WS_CNT    0                    // cnT   [C][P]  = 524288
#define WS_CC     (C*P)                // cc    [P]
#define WS_SSQ    (WS_CC + P)          // ssq   [N]     (sum zq^2 per row)
#define WS_ZQT    (WS_SSQ + N)         // zqT   [C][N]  = 2097152
#define WS_CODEST (WS_ZQT + C*N)       // codesT[C][N]  = 2097152
#define WS_IDX    (WS_CODEST + C*N)    // idx   [N] (int)
#define WS_ACC    (WS_IDX + N)         // loss accumulator (1 float)
// total ~4.8M floats = 19.2 MB

// d_out layout: out [N*F], loss [1], idx-as-float [N]
#define OUT_LOSS_OFF (N*F)
#define OUT_IDX_OFF  (N*F + 1)

// ---------------- K1: normalize codebook -> cnT [C][P], cc [P] ----------------
__global__ __launch_bounds__(256) void k1_norm_codebook(
    const float* __restrict__ cb, float* __restrict__ cnT, float* __restrict__ cc) {
    int p = blockIdx.x * 256 + threadIdx.x;   // one thread per page
    const float4* cb4 = (const float4*)(cb + (size_t)p * C);
    float4 v[16];
    float ss = 0.f;
#pragma unroll
    for (int i = 0; i < 16; ++i) {
        v[i] = cb4[i];
        ss += v[i].x * v[i].x + v[i].y * v[i].y + v[i].z * v[i].z + v[i].w * v[i].w;
    }
    float nrm = sqrtf(ss);
    float s2 = 0.f;
#pragma unroll
    for (int i = 0; i < 16; ++i) {
        float cx = v[i].x / nrm, cy = v[i].y / nrm, cz = v[i].z / nrm, cw = v[i].w / nrm;
        cnT[(i * 4 + 0) * P + p] = cx;
        cnT[(i * 4 + 1) * P + p] = cy;
        cnT[(i * 4 + 2) * P + p] = cz;
        cnT[(i * 4 + 3) * P + p] = cw;
        s2 += cx * cx + cy * cy + cz * cz + cw * cw;
    }
    cc[p] = s2;
}

// ---------------- K2: zq = normalize(z @ w_in^T + b_in) -> zqT [C][N], ssq [N] ----
__global__ __launch_bounds__(256) void k2_project(
    const float* __restrict__ z, const float* __restrict__ w_in, const float* __restrict__ b_in,
    float* __restrict__ zqT, float* __restrict__ ssq_g) {
    __shared__ float zrow[128 * 33];   // padded: bank-conflict <= 4-way
    __shared__ float wrow[64 * 32];
    __shared__ float red[128 * 9];
    int tid = threadIdx.x;
    int tr = tid & 31;        // row group: 4 rows each -> 128 rows
    int tc = tid >> 5;        // code group: 8 codes each -> 64 codes
    int rb = blockIdx.x * 128;

    float y[4][8];
#pragma unroll
    for (int i = 0; i < 4; ++i)
#pragma unroll
        for (int j = 0; j < 8; ++j) y[i][j] = 0.f;

    for (int kt = 0; kt < F; kt += 32) {
        __syncthreads();
        for (int i = tid; i < 128 * 32; i += 256) {
            int r = i >> 5, k = i & 31;
            zrow[r * 33 + k] = z[(size_t)(rb + r) * F + kt + k];
        }
        for (int i = tid; i < 64 * 32; i += 256) {
            int c = i >> 5, k = i & 31;
            wrow[c * 32 + k] = w_in[(size_t)c * F + kt + k];
        }
        __syncthreads();
#pragma unroll
        for (int k4 = 0; k4 < 8; ++k4) {
            float zs[4][4];
#pragma unroll
            for (int i = 0; i < 4; ++i)
#pragma unroll
                for (int kk = 0; kk < 4; ++kk)
                    zs[i][kk] = zrow[(tr * 4 + i) * 33 + k4 * 4 + kk];
#pragma unroll
            for (int j = 0; j < 8; ++j) {
                float4 wv = *(const float4*)&wrow[(tc * 8 + j) * 32 + k4 * 4];
#pragma unroll
                for (int i = 0; i < 4; ++i)
                    y[i][j] = fmaf(zs[i][3], wv.w,
                              fmaf(zs[i][2], wv.z,
                              fmaf(zs[i][1], wv.y,
                              fmaf(zs[i][0], wv.x, y[i][j]))));
            }
        }
    }
    // + b_in (zeros, but keep reference op order)
#pragma unroll
    for (int j = 0; j < 8; ++j) {
        float b = b_in[tc * 8 + j];
#pragma unroll
        for (int i = 0; i < 4; ++i) y[i][j] += b;
    }
    // row norms (sum over 64 codes, spread over 8 threads)
    __syncthreads();
#pragma unroll
    for (int i = 0; i < 4; ++i) {
        float s = 0.f;
#pragma unroll
        for (int j = 0; j < 8; ++j) s += y[i][j] * y[i][j];
        red[(tr * 4 + i) * 9 + tc] = s;
    }
    __syncthreads();
    float nrm[4];
#pragma unroll
    for (int i = 0; i < 4; ++i) {
        float t = 0.f;
#pragma unroll
        for (int t8 = 0; t8 < 8; ++t8) t += red[(tr * 4 + i) * 9 + t8];
        nrm[i] = sqrtf(t);
    }
    float q[4][8];
#pragma unroll
    for (int i = 0; i < 4; ++i)
#pragma unroll
        for (int j = 0; j < 8; ++j) q[i][j] = y[i][j] / nrm[i];
    // ssq of normalized rows (reference computes sum(zq*zq) on normalized zq)
    __syncthreads();
#pragma unroll
    for (int i = 0; i < 4; ++i) {
        float s = 0.f;
#pragma unroll
        for (int j = 0; j < 8; ++j) s += q[i][j] * q[i][j];
        red[(tr * 4 + i) * 9 + tc] = s;
    }
    __syncthreads();
    if (tc == 0) {
#pragma unroll
        for (int i = 0; i < 4; ++i) {
            int r = tr * 4 + i;
            float t = 0.f;
#pragma unroll
            for (int t8 = 0; t8 < 8; ++t8) t += red[r * 9 + t8];
            ssq_g[rb + r] = t;
        }
    }
    // store transposed: zqT[c][rb + tr*4 .. +3]
#pragma unroll
    for (int j = 0; j < 8; ++j) {
        int c = tc * 8 + j;
        float4 o = make_float4(q[0][j], q[1][j], q[2][j], q[3][j]);
        *(float4*)&zqT[(size_t)c * N + rb + tr * 4] = o;
    }
}

// ---------------- K3: fused distance + argmin over pages ----------------
__global__ __launch_bounds__(256) void k3_argmin(
    const float* __restrict__ zqT, const float* __restrict__ cnT,
    const float* __restrict__ cc, const float* __restrict__ ssq,
    int* __restrict__ idx_ws, float* __restrict__ idx_out) {
    __shared__ float zs[64 * 64];    // zqT tile  [k][64 rows]
    __shared__ float cs[64 * 128];   // cnT tile  [k][128 pages]
    __shared__ float rv[64 * 16];
    __shared__ int   ri[64 * 16];
    int tid = threadIdx.x;
    int tx = tid & 15;     // page group: 8 pages each
    int ty = tid >> 4;     // row group: 4 rows each
    int rb = blockIdx.x * 64;

    for (int i = tid; i < 64 * 64; i += 256) {
        int k = i >> 6, r = i & 63;
        zs[k * 64 + r] = zqT[(size_t)k * N + rb + r];
    }
    float ssqr[4];
#pragma unroll
    for (int i = 0; i < 4; ++i) ssqr[i] = ssq[rb + ty * 4 + i];

    float bv[4] = {3.4e38f, 3.4e38f, 3.4e38f, 3.4e38f};
    int   bp[4] = {0, 0, 0, 0};

    for (int pt = 0; pt < P; pt += 128) {
        __syncthreads();
        for (int i = tid; i < 64 * 128; i += 256) {
            int k = i >> 7, p = i & 127;
            cs[k * 128 + p] = cnT[(size_t)k * P + pt + p];
        }
        __syncthreads();
        float acc[4][8];
#pragma unroll
        for (int i = 0; i < 4; ++i)
#pragma unroll
            for (int j = 0; j < 8; ++j) acc[i][j] = 0.f;
#pragma unroll 8
        for (int k = 0; k < 64; ++k) {
            float4 zf = *(const float4*)&zs[k * 64 + ty * 4];
            float4 ca = *(const float4*)&cs[k * 128 + tx * 8];
            float4 cb2 = *(const float4*)&cs[k * 128 + tx * 8 + 4];
            float za[4] = {zf.x, zf.y, zf.z, zf.w};
            float cp[8] = {ca.x, ca.y, ca.z, ca.w, cb2.x, cb2.y, cb2.z, cb2.w};
#pragma unroll
            for (int i = 0; i < 4; ++i)
#pragma unroll
                for (int j = 0; j < 8; ++j)
                    acc[i][j] = fmaf(za[i], cp[j], acc[i][j]);
        }
#pragma unroll
        for (int j = 0; j < 8; ++j) {
            int p = pt + tx * 8 + j;
            float ccp = cc[p];
#pragma unroll
            for (int i = 0; i < 4; ++i) {
                float d = (ssqr[i] + ccp) - 2.0f * acc[i][j];
                if (d < bv[i]) { bv[i] = d; bp[i] = p; }   // strict <: first index wins
            }
        }
    }
    __syncthreads();
#pragma unroll
    for (int i = 0; i < 4; ++i) {
        rv[(ty * 4 + i) * 16 + tx] = bv[i];
        ri[(ty * 4 + i) * 16 + tx] = bp[i];
    }
    __syncthreads();
    if (tid < 64) {
        int r = tid;
        float best = rv[r * 16]; int bi = ri[r * 16];
#pragma unroll
        for (int t = 1; t < 16; ++t) {
            float v = rv[r * 16 + t]; int p = ri[r * 16 + t];
            if (v < best || (v == best && p < bi)) { best = v; bi = p; }
        }
        idx_ws[rb + r] = bi;
        idx_out[rb + r] = (float)bi;
    }
}

// ---------------- K3b: gather codesT[k][r] = cnT[k][idx[r]] ----------------
__global__ __launch_bounds__(256) void k3b_gather(
    const float* __restrict__ cnT, const int* __restrict__ idx, float* __restrict__ codesT) {
    for (size_t i = (size_t)blockIdx.x * 256 + threadIdx.x; i < (size_t)C * N;
         i += (size_t)gridDim.x * 256) {
        int k = (int)(i >> 15);          // N = 2^15
        int r = (int)(i & (N - 1));
        codesT[i] = cnT[(size_t)k * P + idx[r]];
    }
}

// ---------------- K4: out = codes @ w_out^T + b_out ----------------
__global__ __launch_bounds__(256) void k4_out(
    const float* __restrict__ codesT, const float* __restrict__ w_out,
    const float* __restrict__ b_out, float* __restrict__ out) {
    __shared__ float cds[64 * 64];    // codesT tile [k][64 rows]
    __shared__ float wo[64 * 65];     // w_out tile  [k][f], padded
    int tid = threadIdx.x;
    int tx = tid & 15;     // col group: 4 cols each
    int ty = tid >> 4;     // row group: 4 rows each
    int rb = blockIdx.x * 64;

    for (int i = tid; i < 64 * 64; i += 256) {
        int k = i >> 6, r = i & 63;
        cds[k * 64 + r] = codesT[(size_t)k * N + rb + r];
    }
    for (int ft = 0; ft < F; ft += 64) {
        __syncthreads();
        for (int i = tid; i < 64 * 64; i += 256) {
            int k = i & 63, f = i >> 6;
            wo[k * 65 + f] = w_out[(size_t)(ft + f) * C + k];
        }
        __syncthreads();
        float acc[4][4];
#pragma unroll
        for (int i = 0; i < 4; ++i)
#pragma unroll
            for (int j = 0; j < 4; ++j) acc[i][j] = 0.f;
#pragma unroll 8
        for (int k = 0; k < 64; ++k) {
            float4 cf = *(const float4*)&cds[k * 64 + ty * 4];
            float cr[4] = {cf.x, cf.y, cf.z, cf.w};
            float wv[4];
#pragma unroll
            for (int j = 0; j < 4; ++j) wv[j] = wo[k * 65 + tx * 4 + j];
#pragma unroll
            for (int i = 0; i < 4; ++i)
#pragma unroll
                for (int j = 0; j < 4; ++j)
                    acc[i][j] = fmaf(cr[i], wv[j], acc[i][j]);
        }
#pragma unroll
        for (int i = 0; i < 4; ++i) {
            int r = rb + ty * 4 + i;
            float4 o;
            o.x = acc[i][0] + b_out[ft + tx * 4 + 0];
            o.y = acc[i][1] + b_out[ft + tx * 4 + 1];
            o.z = acc[i][2] + b_out[ft + tx * 4 + 2];
            o.w = acc[i][3] + b_out[ft + tx * 4 + 3];
            *(float4*)&out[(size_t)r * F + ft + tx * 4] = o;
        }
    }
}

// ---------------- K5: loss partial sums ----------------
__global__ __launch_bounds__(256) void k5_loss(
    const float* __restrict__ zqT, const float* __restrict__ codesT, float* __restrict__ acc) {
    float s = 0.f;
    for (size_t i = (size_t)blockIdx.x * 256 + threadIdx.x; i < (size_t)C * N;
         i += (size_t)gridDim.x * 256) {
        float d = zqT[i] - codesT[i];
        s = fmaf(d, d, s);
    }
#pragma unroll
    for (int off = 32; off > 0; off >>= 1) s += __shfl_xor(s, off);
    __shared__ float wsum[4];
    int lane = threadIdx.x & 63, wv = threadIdx.x >> 6;
    if (lane == 0) wsum[wv] = s;
    __syncthreads();
    if (threadIdx.x == 0) atomicAdd(acc, wsum[0] + wsum[1] + wsum[2] + wsum[3]);
}

// ---------------- K6: finalize loss ----------------
__global__ void k6_finalize(const float* __restrict__ acc, float* __restrict__ loss_out) {
    float m = acc[0] / (float)(C * N);
    loss_out[0] = 0.25f * m + m;   // BETA*mean + mean
}

extern "C" void kernel_launch(void* const* d_in, const int* in_sizes, int n_in,
                              void* d_out, int out_size, void* d_ws, size_t ws_size,
                              hipStream_t stream) {
    const float* z      = (const float*)d_in[0];
    const float* w_in   = (const float*)d_in[1];
    const float* b_in   = (const float*)d_in[2];
    const float* w_out  = (const float*)d_in[3];
    const float* b_out  = (const float*)d_in[4];
    const float* cb     = (const float*)d_in[5];
    float* out = (float*)d_out;
    float* ws  = (float*)d_ws;

    hipMemsetAsync(ws + WS_ACC, 0, sizeof(float), stream);
    k1_norm_codebook<<<P / 256, 256, 0, stream>>>(cb, ws + WS_CNT, ws + WS_CC);
    k2_project<<<N / 128, 256, 0, stream>>>(z, w_in, b_in, ws + WS_ZQT, ws + WS_SSQ);
    k3_argmin<<<N / 64, 256, 0, stream>>>(ws + WS_ZQT, ws + WS_CNT, ws + WS_CC, ws + WS_SSQ,
                                          (int*)(ws + WS_IDX), out + OUT_IDX_OFF);
    k3b_gather<<<2048, 256, 0, stream>>>(ws + WS_CNT, (const int*)(ws + WS_IDX), ws + WS_CODEST);
    k4_out<<<N / 64, 256, 0, stream>>>(ws + WS_CODEST, w_out, b_out, out);
    k5_loss<<<2048, 256, 0, stream>>>(ws + WS_ZQT, ws + WS_CODEST, ws + WS_ACC);
    k6_finalize<<<1, 1, 0, stream>>>(ws + WS_ACC, out + OUT_LOSS_OFF);
}